// Round 2
// baseline (1735.550 us; speedup 1.0000x reference)
//
#include <hip/hip_runtime.h>

#define IN_CAPS 1152
#define OUT_CH 32
#define BLOCK 384                      // 6 waves; 3 rows/thread; 2 blocks/CU target
#define NWAVES (BLOCK / 64)            // 6
#define RPT (IN_CAPS / BLOCK)          // 3
#define EPS 1e-8f

// Channel-split butterfly over the 64-lane wave (31+1 shuffles), then cross-wave
// LDS reduce + squash into vsh. Destroys acc. Verified numerics (round-1 absmax 0).
__device__ __forceinline__ void reduce_squash(float acc[OUT_CH],
                                              float* __restrict__ swred,
                                              float* __restrict__ vsh,
                                              const int t, const int lane, const int wave)
{
    #pragma unroll
    for (int st = 0; st < 5; ++st) {
        const int m    = 1 << st;
        const int half = 16 >> st;
        const bool up  = (lane & m) != 0;
        #pragma unroll
        for (int j = 0; j < half; ++j) {
            const float send = up ? acc[j] : acc[half + j];
            const float keep = up ? acc[half + j] : acc[j];
            acc[j] = keep + __shfl_xor(send, m);
        }
    }
    acc[0] += __shfl_xor(acc[0], 32);   // merge the two 32-lane halves

    const int l5 = lane & 31;
    const int ch = ((l5 & 1) << 4) | ((l5 & 2) << 2) | (l5 & 4)
                 | ((l5 & 8) >> 2) | ((l5 & 16) >> 4);   // bitrev5: lane -> channel
    if (lane < 32) swred[wave * OUT_CH + ch] = acc[0];
    __syncthreads();
    if (t < OUT_CH) {
        float s = 0.f;
        #pragma unroll
        for (int w = 0; w < NWAVES; ++w) s += swred[w * OUT_CH + t];
        float n2 = s * s;
        #pragma unroll
        for (int m2 = 1; m2 <= 16; m2 <<= 1) n2 += __shfl_xor(n2, m2);
        const float scale = n2 / ((1.0f + n2) * sqrtf(n2 + EPS));
        vsh[t] = s * scale;
    }
    __syncthreads();
}

__global__ __launch_bounds__(BLOCK)
__attribute__((amdgpu_waves_per_eu(3, 3)))   // pin: exactly 3 waves/SIMD -> VGPR cap 170, no spill-for-occupancy
void caps_route(const float* __restrict__ u_hat,
                const float* __restrict__ c0,
                const int* __restrict__ routings_p,
                float* __restrict__ out)
{
    __shared__ float swred[NWAVES * OUT_CH];   // 768 B
    __shared__ float vsh[OUT_CH];              // 128 B

    const int t    = threadIdx.x;
    const int n    = blockIdx.x;
    const int lane = t & 63;
    const int wave = t >> 6;

    const float4* __restrict__ u4 =
        reinterpret_cast<const float4*>(u_hat) + (size_t)n * (IN_CAPS * OUT_CH / 4);
    const float4* __restrict__ c4 = reinterpret_cast<const float4*>(c0);

    // ---------- load this thread's 3 rows of u into registers (the ONLY HBM sweep of u) ----------
    // Wave's rows are contiguous (rows t..t+63 per group): dense 8 KB footprint per wave-group,
    // full cache-line utilization across the k-loop.
    float u[RPT][OUT_CH];
    #pragma unroll
    for (int s = 0; s < RPT; ++s) {
        const float4* __restrict__ row = u4 + (size_t)(t + s * BLOCK) * (OUT_CH / 4);
        #pragma unroll
        for (int k = 0; k < OUT_CH / 4; ++k) {
            const float4 q = row[k];
            u[s][4*k+0] = q.x; u[s][4*k+1] = q.y; u[s][4*k+2] = q.z; u[s][4*k+3] = q.w;
        }
    }

    // ---------- sweep 1: acc[j] = sum over owned rows of u[i,j]*c0[i,j] ----------
    // c loaded in half-row chunks (4 float4 in flight) to bound register pressure.
    float acc[OUT_CH];
    #pragma unroll
    for (int j = 0; j < OUT_CH; ++j) acc[j] = 0.f;
    #pragma unroll
    for (int s = 0; s < RPT; ++s) {
        const float4* __restrict__ crow = c4 + (size_t)(t + s * BLOCK) * (OUT_CH / 4);
        #pragma unroll
        for (int h = 0; h < 2; ++h) {
            float4 cq[4];
            #pragma unroll
            for (int k = 0; k < 4; ++k) cq[k] = crow[h * 4 + k];
            #pragma unroll
            for (int k = 0; k < 4; ++k) {
                const int j = h * 16 + 4 * k;
                acc[j+0] = fmaf(u[s][j+0], cq[k].x, acc[j+0]);
                acc[j+1] = fmaf(u[s][j+1], cq[k].y, acc[j+1]);
                acc[j+2] = fmaf(u[s][j+2], cq[k].z, acc[j+2]);
                acc[j+3] = fmaf(u[s][j+3], cq[k].w, acc[j+3]);
            }
        }
    }
    reduce_squash(acc, swred, vsh, t, lane, wave);

    // ---------- routing sweeps: u stays in registers; v is wave-uniform -> SGPRs ----------
    const int iters = routings_p[0] - 1;
    for (int it = 0; it < iters; ++it) {
        float v[OUT_CH];
        #pragma unroll
        for (int j = 0; j < OUT_CH; ++j)
            v[j] = __uint_as_float(__builtin_amdgcn_readfirstlane(__float_as_uint(vsh[j])));

        #pragma unroll
        for (int j = 0; j < OUT_CH; ++j) acc[j] = 0.f;

        #pragma unroll
        for (int s = 0; s < RPT; ++s) {
            // thread-local softmax over channels; max-subtraction skipped (|u*v| small, fp32 exp safe)
            float e[OUT_CH];
            float sum = 0.f;
            #pragma unroll
            for (int j = 0; j < OUT_CH; ++j) {
                e[j] = __expf(u[s][j] * v[j]);
                sum += e[j];
            }
            const float w = __builtin_amdgcn_rcpf(sum);
            #pragma unroll
            for (int j = 0; j < OUT_CH; ++j)
                acc[j] = fmaf(u[s][j] * e[j], w, acc[j]);
        }
        reduce_squash(acc, swred, vsh, t, lane, wave);
    }

    if (t < OUT_CH)
        out[(size_t)n * OUT_CH + t] = vsh[t] * 0.5f + 0.5f;
}

extern "C" void kernel_launch(void* const* d_in, const int* in_sizes, int n_in,
                              void* d_out, int out_size, void* d_ws, size_t ws_size,
                              hipStream_t stream) {
    const float* u_hat   = (const float*)d_in[0];
    const float* c0      = (const float*)d_in[1];
    const int*   routing = (const int*)d_in[2];
    float* out = (float*)d_out;

    const int N = in_sizes[0] / (IN_CAPS * OUT_CH);   // 4096
    caps_route<<<dim3(N), dim3(BLOCK), 0, stream>>>(u_hat, c0, routing, out);
}